// Round 9
// baseline (208.417 us; speedup 1.0000x reference)
//
#include <hip/hip_runtime.h>
#include <hip/hip_bf16.h>

typedef __hip_bfloat16 bf16;
typedef __attribute__((ext_vector_type(8))) short short8;
typedef __attribute__((ext_vector_type(4))) float f32x4;

#define SS 512
#define HD 768
#define NEGC (-1e30f)
#define NSPLIT 16
#define TOK 32                       // SS / NSPLIT
#define POOL_BLOCKS 3072             // 96 groups(4 spans) * 2 batch * 16 splits
#define D1_BLOCKS (POOL_BLOCKS + 4)

// ---------------------------------------------------------------------------
// f32x8 -> bf16x8 in-register convert (for MFMA W operand)
// ---------------------------------------------------------------------------
__device__ __forceinline__ short8 cvt8(float4 a, float4 b)
{
  union { bf16 h[8]; short8 s; } u;
  u.h[0] = __hip_bfloat16(a.x); u.h[1] = __hip_bfloat16(a.y);
  u.h[2] = __hip_bfloat16(a.z); u.h[3] = __hip_bfloat16(a.w);
  u.h[4] = __hip_bfloat16(b.x); u.h[5] = __hip_bfloat16(b.y);
  u.h[6] = __hip_bfloat16(b.z); u.h[7] = __hip_bfloat16(b.w);
  return u.s;
}

// ---------------------------------------------------------------------------
// Dispatch 1: pool partials (bx<3072) | aux (last 4 blocks).
// Pool: 4 spans/block (vs round-8's 8) -> 8 blocks/CU (full 32-wave cap) and
// ~28 VALU/token instead of ~50; same total work, 2x the latency hiding.
// 32 tokens (split sp of 16), 3 consecutive h/thread (one 12B load/token).
// Branch-free cndmask keeps the 12 accumulators in VGPRs.
// ---------------------------------------------------------------------------
__global__ __launch_bounds__(256) void k_d1(
    const int* __restrict__ e_masks, const int* __restrict__ m_masks,
    const int* __restrict__ r_masks, const int* __restrict__ c_masks,
    const float* __restrict__ emb, const int* __restrict__ input_ids,
    const int* __restrict__ esizes, const int* __restrict__ msizes,
    const float* __restrict__ nsemb, const float* __restrict__ esemb,
    bf16* __restrict__ part, int* __restrict__ flags,
    bf16* __restrict__ sze, bf16* __restrict__ szm,
    bf16* __restrict__ ctxb, float* __restrict__ out)
{
  int bx = blockIdx.x;
  int t  = threadIdx.x;

  if (bx >= POOL_BLOCKS) {
    // ---------------- aux ----------------
    int q = bx - POOL_BLOCKS;
    if (q == 0) {            // entity size-emb table [128][32] bf16
      for (int i = t; i < 128 * 32; i += 256)
        sze[i] = __hip_bfloat16(nsemb[(size_t)esizes[i >> 5] * 32 + (i & 31)]);
    } else if (q == 1) {     // mention size-emb table
      for (int i = t; i < 128 * 32; i += 256)
        szm[i] = __hip_bfloat16(esemb[(size_t)msizes[i >> 5] * 32 + (i & 31)]);
    } else if (q == 2) {     // bf16 cls-ctx rows, both batches
      __shared__ int s_cls;
      for (int b2 = 0; b2 < 2; b2++) {
        if (t == 0) s_cls = SS;
        __syncthreads();
        for (int s = t; s < SS; s += 256)
          if (input_ids[b2 * SS + s] == 101) atomicMin(&s_cls, s);
        __syncthreads();
        int ci = (s_cls == SS) ? 0 : s_cls;
        for (int hh = t; hh < HD; hh += 256)
          ctxb[(size_t)b2 * HD + hh] = __hip_bfloat16(emb[((size_t)b2 * SS + ci) * HD + hh]);
        __syncthreads();
      }
    } else {                 // zero d_out (3840 floats) for head atomics
      for (int i = t; i < 3840; i += 256) out[i] = 0.f;
    }
    return;
  }

  // ---------------- pooling partials: 4 spans ----------------
  int g  = bx % 96;              // span group (4 spans)
  int b  = (bx / 96) & 1;        // batch
  int sp = bx / 192;             // S-split 0..15 (32 tokens each)
  int j0 = g * 4;

  const int* marr; int row0;
  if      (j0 < 64)  { marr = e_masks; row0 = b*64  +  j0;        }
  else if (j0 < 128) { marr = m_masks; row0 = b*64  + (j0-64);    }
  else if (j0 < 256) { marr = r_masks; row0 = b*128 + (j0-128);   }
  else               { marr = c_masks; row0 = b*128 + (j0-256);   }

  __shared__ unsigned s_pack[TOK];
  __shared__ unsigned s_any;
  if (t == 0) s_any = 0u;
  __syncthreads();

  int sbase = sp * TOK;
  if (t < TOK) {
    unsigned w = 0;
    #pragma unroll
    for (int k = 0; k < 4; k++) {
      int mm = marr[(size_t)(row0 + k) * SS + sbase + t];
      w |= (mm != 0 ? 1u : 0u) << k;
    }
    s_pack[t] = w;
    atomicOr(&s_any, w);
  }
  __syncthreads();

  float a0[4], a1[4], a2[4];
  #pragma unroll
  for (int k = 0; k < 4; k++) { a0[k] = -INFINITY; a1[k] = -INFINITY; a2[k] = -INFINITY; }

  // 3 consecutive h per thread -> one 12B load per token
  const float* ep = emb + ((size_t)b * SS + sbase) * HD + t * 3;
  #pragma unroll 4
  for (int s = 0; s < TOK; s++) {
    float v0 = ep[0];
    float v1 = ep[1];
    float v2 = ep[2];
    ep += HD;
    unsigned wm = s_pack[s];
    #pragma unroll
    for (int k = 0; k < 4; k++) {
      float add = (wm & (1u << k)) ? 0.f : NEGC;
      a0[k] = fmaxf(a0[k], v0 + add);
      a1[k] = fmaxf(a1[k], v1 + add);
      a2[k] = fmaxf(a2[k], v2 + add);
    }
  }

  #pragma unroll
  for (int k = 0; k < 4; k++) {
    int sg = b * 384 + j0 + k;
    bf16* dst = part + ((size_t)sp * 768 + sg) * HD + t * 3;
    dst[0] = __hip_bfloat16(a0[k]);
    dst[1] = __hip_bfloat16(a1[k]);
    dst[2] = __hip_bfloat16(a2[k]);
  }
  if (t < 4) flags[sp * 768 + b * 384 + j0 + t] = (int)((s_any >> t) & 1u);
}

// ---------------------------------------------------------------------------
// Dispatch 2: combine the 16 S-split partials -> final bf16 pools / ctx.
// grid 768 (span-global), block 256 (3 consecutive h each).
// ---------------------------------------------------------------------------
__global__ __launch_bounds__(256) void k_combine(
    const bf16* __restrict__ part, const int* __restrict__ flags,
    bf16* __restrict__ epool, bf16* __restrict__ mpool,
    bf16* __restrict__ rctx, bf16* __restrict__ cctx)
{
  int sg = blockIdx.x;
  int b = sg / 384, j = sg % 384;
  int any = 0;
  #pragma unroll
  for (int sp = 0; sp < NSPLIT; sp++) any |= flags[sp * 768 + sg];

  int h = threadIdx.x * 3;
  float v0 = -INFINITY, v1 = -INFINITY, v2 = -INFINITY;
  #pragma unroll
  for (int sp = 0; sp < NSPLIT; sp++) {
    const bf16* src = part + ((size_t)sp * 768 + sg) * HD + h;
    v0 = fmaxf(v0, (float)src[0]);
    v1 = fmaxf(v1, (float)src[1]);
    v2 = fmaxf(v2, (float)src[2]);
  }
  bf16* dst;
  if      (j < 64)  { dst = epool + ((size_t)b*64  + j)       * HD + h; }
  else if (j < 128) { dst = mpool + ((size_t)b*64  + (j-64))  * HD + h; }
  else if (j < 256) { dst = rctx  + ((size_t)b*128 + (j-128)) * HD + h;
                      if (!any) { v0 = 0.f; v1 = 0.f; v2 = 0.f; } }
  else              { dst = cctx  + ((size_t)b*128 + (j-256)) * HD + h;
                      if (!any) { v0 = 0.f; v1 = 0.f; v2 = 0.f; } }
  dst[0] = __hip_bfloat16(v0);
  dst[1] = __hip_bfloat16(v1);
  dst[2] = __hip_bfloat16(v2);
}

// ---------------------------------------------------------------------------
// GEMM layer 1: A gathered bf16, W loaded f32 + in-register cvt.
// grid (8,24,4), block 256 = 4 waves K-split + LDS reduce.
// Span problems (z<2): head fused via f32 atomicAdd. Rel (z>=2): store RH1/CH1.
// ---------------------------------------------------------------------------
struct P1 {
  const bf16 *ctx, *pool, *sz; const int* ridx;
  const float* W; const float* bias;
  bf16* C;                 // null for span problems
  const float *hw, *hb; float* outp;
  int is_rel, N, K, Mtiles;
};
struct P1x4 { P1 p[4]; };

__global__ __launch_bounds__(256, 2) void k_gemm1(P1x4 args)
{
  P1 g = args.p[blockIdx.z];
  int x = blockIdx.x;
  if (x >= g.Mtiles) return;
  int mt = x * 32, nt = blockIdx.y * 32;
  int wave = threadIdx.x >> 6, lane = threadIdx.x & 63;
  int lm = lane & 15, quad = lane >> 4;
  int K_ = g.K;

  const bf16 *g0[2], *g1[2], *g2[2], *g3[2], *g4[2];
  int rr[2] = { mt + lm, mt + 16 + lm };
  #pragma unroll
  for (int i = 0; i < 2; i++) {
    int r = rr[i];
    if (g.is_rel) {
      int b = r >> 7;
      int i0 = g.ridx[2 * r], i1 = g.ridx[2 * r + 1];
      g0[i] = g.ctx  + (size_t)r * HD;
      g1[i] = g.pool + (size_t)(b * 64 + i0) * HD;
      g2[i] = g.pool + (size_t)(b * 64 + i1) * HD;
      g3[i] = g.sz   + (size_t)(b * 64 + i0) * 32;
      g4[i] = g.sz   + (size_t)(b * 64 + i1) * 32;
    } else {
      g0[i] = g.ctx  + (size_t)(r >> 6) * HD;
      g1[i] = g.pool + (size_t)r * HD;
      g2[i] = g.sz   + (size_t)r * 32;
      g3[i] = g2[i]; g4[i] = g2[i];
    }
  }
  const float* w0p = g.W + (size_t)(nt + lm)      * K_ + quad * 8;
  const float* w1p = g.W + (size_t)(nt + 16 + lm) * K_ + quad * 8;

  f32x4 acc00 = {0.f,0.f,0.f,0.f}, acc01 = {0.f,0.f,0.f,0.f};
  f32x4 acc10 = {0.f,0.f,0.f,0.f}, acc11 = {0.f,0.f,0.f,0.f};

  for (int k32 = wave * 32; k32 < K_; k32 += 128) {
    const bf16 *b0, *b1;
    if      (k32 < 768)  { b0 = g0[0] + k32;          b1 = g0[1] + k32;          }
    else if (k32 < 1536) { b0 = g1[0] + (k32 - 768);  b1 = g1[1] + (k32 - 768);  }
    else if (k32 < 2304) { b0 = g2[0] + (k32 - 1536); b1 = g2[1] + (k32 - 1536); }
    else if (k32 < 2336) { b0 = g3[0] + (k32 - 2304); b1 = g3[1] + (k32 - 2304); }
    else                 { b0 = g4[0] + (k32 - 2336); b1 = g4[1] + (k32 - 2336); }
    short8 a0 = *(const short8*)((const short*)b0 + quad * 8);
    short8 a1 = *(const short8*)((const short*)b1 + quad * 8);
    const float* wq0 = w0p + k32;
    const float* wq1 = w1p + k32;
    short8 w0 = cvt8(*(const float4*)wq0, *(const float4*)(wq0 + 4));
    short8 w1 = cvt8(*(const float4*)wq1, *(const float4*)(wq1 + 4));
    acc00 = __builtin_amdgcn_mfma_f32_16x16x32_bf16(a0, w0, acc00, 0, 0, 0);
    acc01 = __builtin_amdgcn_mfma_f32_16x16x32_bf16(a0, w1, acc01, 0, 0, 0);
    acc10 = __builtin_amdgcn_mfma_f32_16x16x32_bf16(a1, w0, acc10, 0, 0, 0);
    acc11 = __builtin_amdgcn_mfma_f32_16x16x32_bf16(a1, w1, acc11, 0, 0, 0);
  }

  __shared__ float smem[4 * 32 * 32];
  #pragma unroll
  for (int reg = 0; reg < 4; reg++) {
    int r = quad * 4 + reg;
    smem[wave*1024 + r*32 + lm]             = acc00[reg];
    smem[wave*1024 + r*32 + 16 + lm]        = acc01[reg];
    smem[wave*1024 + (16 + r)*32 + lm]      = acc10[reg];
    smem[wave*1024 + (16 + r)*32 + 16 + lm] = acc11[reg];
  }
  __syncthreads();

  int c = threadIdx.x & 31;
  int rb = threadIdx.x >> 5;
  float bb = g.bias[nt + c];
  #pragma unroll
  for (int i = 0; i < 4; i++) {
    int r = rb + 8 * i;
    float v = smem[r*32 + c] + smem[1024 + r*32 + c] + smem[2048 + r*32 + c] + smem[3072 + r*32 + c];
    v = fmaxf(v + bb, 0.f);
    if (g.C) g.C[(size_t)(mt + r) * HD + nt + c] = __hip_bfloat16(v);
    else     smem[r*32 + c] = v;
  }
  __syncthreads();

  if (!g.C) {   // fused span head
    int r = threadIdx.x >> 3, oi = threadIdx.x & 7;
    for (int o = oi; o < g.N; o += 8) {
      float s = 0.f;
      #pragma unroll
      for (int cc = 0; cc < 32; cc++) {
        int c2 = (cc + r) & 31;
        s += smem[r*32 + c2] * g.hw[(size_t)o * HD + nt + c2];
      }
      if (blockIdx.y == 0) s += g.hb[o];
      atomicAdd(g.outp + (size_t)(mt + r) * g.N + o, s);
    }
  }
}

// ---------------------------------------------------------------------------
// GEMM layer 2: A bf16 contiguous, W f32 + in-register cvt, fused rel/cr
// heads. grid (8,24,2), block 256.
// ---------------------------------------------------------------------------
struct P2 { const short* A; const float* W; const float* bias;
            const float *hw, *hb; float* outp; int N; };
struct P2x2 { P2 p[2]; };

__global__ __launch_bounds__(256, 2) void k_gemm2(P2x2 args)
{
  P2 g = args.p[blockIdx.z];
  int mt = blockIdx.x * 32, nt = blockIdx.y * 32;
  int wave = threadIdx.x >> 6, lane = threadIdx.x & 63;
  int lm = lane & 15, quad = lane >> 4;

  const short* a0p = g.A + (size_t)(mt + lm)      * HD + quad * 8;
  const short* a1p = g.A + (size_t)(mt + 16 + lm) * HD + quad * 8;
  const float* w0p = g.W + (size_t)(nt + lm)      * HD + quad * 8;
  const float* w1p = g.W + (size_t)(nt + 16 + lm) * HD + quad * 8;

  f32x4 acc00 = {0.f,0.f,0.f,0.f}, acc01 = {0.f,0.f,0.f,0.f};
  f32x4 acc10 = {0.f,0.f,0.f,0.f}, acc11 = {0.f,0.f,0.f,0.f};

  for (int k32 = wave * 32; k32 < HD; k32 += 128) {
    short8 a0 = *(const short8*)(a0p + k32);
    short8 a1 = *(const short8*)(a1p + k32);
    short8 w0 = cvt8(*(const float4*)(w0p + k32), *(const float4*)(w0p + k32 + 4));
    short8 w1 = cvt8(*(const float4*)(w1p + k32), *(const float4*)(w1p + k32 + 4));
    acc00 = __builtin_amdgcn_mfma_f32_16x16x32_bf16(a0, w0, acc00, 0, 0, 0);
    acc01 = __builtin_amdgcn_mfma_f32_16x16x32_bf16(a0, w1, acc01, 0, 0, 0);
    acc10 = __builtin_amdgcn_mfma_f32_16x16x32_bf16(a1, w0, acc10, 0, 0, 0);
    acc11 = __builtin_amdgcn_mfma_f32_16x16x32_bf16(a1, w1, acc11, 0, 0, 0);
  }

  __shared__ float smem[4 * 32 * 32];
  #pragma unroll
  for (int reg = 0; reg < 4; reg++) {
    int r = quad * 4 + reg;
    smem[wave*1024 + r*32 + lm]             = acc00[reg];
    smem[wave*1024 + r*32 + 16 + lm]        = acc01[reg];
    smem[wave*1024 + (16 + r)*32 + lm]      = acc10[reg];
    smem[wave*1024 + (16 + r)*32 + 16 + lm] = acc11[reg];
  }
  __syncthreads();

  int c = threadIdx.x & 31;
  int rb = threadIdx.x >> 5;
  float bb = g.bias[nt + c];
  #pragma unroll
  for (int i = 0; i < 4; i++) {
    int r = rb + 8 * i;
    float v = smem[r*32 + c] + smem[1024 + r*32 + c] + smem[2048 + r*32 + c] + smem[3072 + r*32 + c];
    smem[r*32 + c] = fmaxf(v + bb, 0.f);
  }
  __syncthreads();

  int r = threadIdx.x >> 3, oi = threadIdx.x & 7;
  for (int o = oi; o < g.N; o += 8) {
    float s = 0.f;
    #pragma unroll
    for (int cc = 0; cc < 32; cc++) {
      int c2 = (cc + r) & 31;
      s += smem[r*32 + c2] * g.hw[(size_t)o * HD + nt + c2];
    }
    if (blockIdx.y == 0) s += g.hb[o];
    atomicAdd(g.outp + (size_t)(mt + r) * g.N + o, s);
  }
}

// ---------------------------------------------------------------------------
extern "C" void kernel_launch(void* const* d_in, const int* in_sizes, int n_in,
                              void* d_out, int out_size, void* d_ws, size_t ws_size,
                              hipStream_t stream)
{
  const int*   input_ids  = (const int*)d_in[0];
  const int*   e_masks    = (const int*)d_in[1];
  const int*   e_sizes    = (const int*)d_in[2];
  const int*   m_masks    = (const int*)d_in[3];
  const int*   m_sizes    = (const int*)d_in[4];
  const int*   relations  = (const int*)d_in[5];
  const int*   r_masks    = (const int*)d_in[6];
  const int*   references = (const int*)d_in[7];
  const int*   c_masks    = (const int*)d_in[8];
  const float* emb        = (const float*)d_in[9];
  const float* nsemb      = (const float*)d_in[10];
  const float* esemb      = (const float*)d_in[11];
  const float* ner_rep_w  = (const float*)d_in[12];
  const float* ner_rep_b  = (const float*)d_in[13];
  const float* ner_head_w = (const float*)d_in[14];
  const float* ner_head_b = (const float*)d_in[15];
  const float* emd_rep_w  = (const float*)d_in[16];
  const float* emd_rep_b  = (const float*)d_in[17];
  const float* emd_head_w = (const float*)d_in[18];
  const float* emd_head_b = (const float*)d_in[19];
  const float* rel_w1 = (const float*)d_in[20];
  const float* rel_b1 = (const float*)d_in[21];
  const float* rel_w2 = (const float*)d_in[22];
  const float* rel_b2 = (const float*)d_in[23];
  const float* rel_w3 = (const float*)d_in[24];
  const float* rel_b3 = (const float*)d_in[25];
  const float* cr_w1 = (const float*)d_in[26];
  const float* cr_b1 = (const float*)d_in[27];
  const float* cr_w2 = (const float*)d_in[28];
  const float* cr_b2 = (const float*)d_in[29];
  const float* cr_w3 = (const float*)d_in[30];
  const float* cr_b3 = (const float*)d_in[31];
  float* out = (float*)d_out;

  // ---- workspace carve ----
  bf16* wsb = (bf16*)d_ws;
  size_t ob = 0;
  bf16* PART  = wsb + ob; ob += (size_t)NSPLIT * 768 * HD;
  bf16* EPOOL = wsb + ob; ob += (size_t)128 * HD;
  bf16* MPOOL = wsb + ob; ob += (size_t)128 * HD;
  bf16* RCTX  = wsb + ob; ob += (size_t)256 * HD;
  bf16* CCTX  = wsb + ob; ob += (size_t)256 * HD;
  bf16* SZE   = wsb + ob; ob += (size_t)128 * 32;
  bf16* SZM   = wsb + ob; ob += (size_t)128 * 32;
  bf16* CTXB  = wsb + ob; ob += (size_t)2 * HD;
  bf16* RH1   = wsb + ob; ob += (size_t)256 * HD;
  bf16* CH1   = wsb + ob; ob += (size_t)256 * HD;
  int*  FLAGS = (int*)(wsb + ob); ob += (size_t)2 * NSPLIT * 768;

  // 1) pool partials (4 spans/block, 8 blocks/CU) + aux
  k_d1<<<D1_BLOCKS, 256, 0, stream>>>(
      e_masks, m_masks, r_masks, c_masks, emb, input_ids,
      e_sizes, m_sizes, nsemb, esemb,
      PART, FLAGS, SZE, SZM, CTXB, out);

  // 2) combine
  k_combine<<<768, 256, 0, stream>>>(PART, FLAGS, EPOOL, MPOOL, RCTX, CCTX);

  // 3) GEMM layer 1 (gathered A, f32 W) + fused span heads
  P1x4 a1;
  a1.p[0] = { CTXB, EPOOL, SZE, nullptr,    ner_rep_w, ner_rep_b,
              nullptr, ner_head_w, ner_head_b, out,        0, 10, 1568, 4 };
  a1.p[1] = { CTXB, MPOOL, SZM, nullptr,    emd_rep_w, emd_rep_b,
              nullptr, emd_head_w, emd_head_b, out + 3328, 0, 2,  1568, 4 };
  a1.p[2] = { RCTX, EPOOL, SZE, relations,  rel_w1, rel_b1,
              RH1, nullptr, nullptr, nullptr,              1, 0,  2368, 8 };
  a1.p[3] = { CCTX, MPOOL, SZM, references, cr_w1, cr_b1,
              CH1, nullptr, nullptr, nullptr,              1, 0,  2368, 8 };
  k_gemm1<<<dim3(8, 24, 4), 256, 0, stream>>>(a1);

  // 4) GEMM layer 2 (f32 W) + fused rel/cr heads
  P2x2 a2;
  a2.p[0] = { (const short*)RH1, rel_w2, rel_b2, rel_w3, rel_b3, out + 1280, 8 };
  a2.p[1] = { (const short*)CH1, cr_w2,  cr_b2,  cr_w3,  cr_b3,  out + 3584, 1 };
  k_gemm2<<<dim3(8, 24, 2), 256, 0, stream>>>(a2);
}